// Round 3
// baseline (189.966 us; speedup 1.0000x reference)
//
#include <hip/hip_runtime.h>
#include <hip/hip_cooperative_groups.h>
#include <stdint.h>

namespace cg = cooperative_groups;

#define B 256
#define DIM 512
#define TOPK 4096
#define MARGIN 0.2f

// ---------------- ws layout ----------------
// ghist : u32 [6144]  @ 0       (3 x 2048 buckets: pass0 / pass1 / pass2)
// part  : double[256] @ 24576

// Parallel radix-select step over a descending-ordered histogram.
// Thread tid owns chunk (255-tid): buckets [(255-tid)*PER, ...+PER).
// Inclusive shuffle-scan over tids == suffix sums over buckets.
// Writes res[0]=selected bucket, res[1]=remaining needed within it.
template <int PER>
__device__ __forceinline__ void radix_select(const uint32_t* __restrict__ gh,
                                             uint32_t needed,
                                             uint32_t* wtot, uint32_t* res, int tid) {
    const int chunk = 255 - tid;
    uint32_t vals[PER];
    uint32_t v = 0;
#pragma unroll
    for (int k = 0; k < PER; ++k) { vals[k] = gh[chunk * PER + k]; v += vals[k]; }
    uint32_t s = v;
    const int lane = tid & 63, wid = tid >> 6;
#pragma unroll
    for (int d = 1; d < 64; d <<= 1) {
        uint32_t t = __shfl_up(s, d, 64);
        if (lane >= d) s += t;
    }
    if (lane == 63) wtot[wid] = s;
    __syncthreads();
    uint32_t off = 0;
    for (int w = 0; w < wid; ++w) off += wtot[w];
    s += off;                         // count in all buckets >= chunk*PER
    const uint32_t excl = s - v;      // count in buckets strictly above own chunk
    if (excl < needed && needed <= s) {
        uint32_t cum = excl;
        int sel = chunk * PER;
        uint32_t nn = needed - excl;
#pragma unroll
        for (int k = PER - 1; k >= 0; --k) {
            const uint32_t h = vals[k];
            if (cum + h >= needed) { sel = chunk * PER + k; nn = needed - cum; break; }
            cum += h;
        }
        res[0] = (uint32_t)sel;
        res[1] = nn;
    }
    __syncthreads();
}

__global__ void __launch_bounds__(256, 1)
fused_kernel(const float* __restrict__ x, const int* __restrict__ lab,
             uint32_t* __restrict__ ghist, double* __restrict__ part,
             float* __restrict__ out) {
    cg::grid_group grid = cg::this_grid();
    __shared__ float    sD[B];
    __shared__ int      sL[B];
    __shared__ uint32_t sh[2048];
    __shared__ uint32_t wtot[4];
    __shared__ uint32_t res[2];
    __shared__ double   wsum[4];

    const int q   = blockIdx.x;
    const int tid = threadIdx.x;
    uint32_t* ghA = ghist;
    uint32_t* ghB = ghist + 2048;
    uint32_t* ghC = ghist + 4096;

    // ---- P0: zero hist buffers + compute D[q][tid] into LDS ----
    {
        const int gidx = q * 256 + tid;
        if (gidx < 6144) ghist[gidx] = 0;
        float* xi = (float*)sh;                 // alias sh as x_q staging
        for (int k = tid; k < DIM; k += 256) xi[k] = x[q * DIM + k];
        sL[tid] = lab[tid];
        __syncthreads();
        const float4* xj4 = (const float4*)(x + tid * DIM);
        float acc = 0.f;
#pragma unroll 4
        for (int k4 = 0; k4 < DIM / 4; ++k4) {
            float4 b = xj4[k4];
            float d0 = xi[k4 * 4 + 0] - b.x;
            float d1 = xi[k4 * 4 + 1] - b.y;
            float d2 = xi[k4 * 4 + 2] - b.z;
            float d3 = xi[k4 * 4 + 3] - b.w;
            acc += d0 * d0 + d1 * d1 + d2 * d2 + d3 * d3;
        }
        sD[tid] = acc;
    }
    grid.sync();

    const int   lq     = sL[q];
    const bool  nvalid = (sL[tid] != lq);
    const float dqn    = sD[tid];

    // ---- P1: histogram pass 0 (bits[31:21]) ----
    for (int i = tid; i < 2048; i += 256) sh[i] = 0;
    __syncthreads();
    for (int p = 0; p < q; ++p) {
        if (sL[p] != lq) continue;
        const float base = sD[p] + MARGIN;
        if (nvalid) {
            const uint32_t bits = __float_as_uint(fmaxf(base - dqn, 0.0f));
            atomicAdd(&sh[bits >> 21], 1u);
        }
    }
    __syncthreads();
    for (int i = tid; i < 2048; i += 256) { uint32_t c = sh[i]; if (c) atomicAdd(&ghA[i], c); }
    grid.sync();

    // ---- P2: select pass 0 + histogram pass 1 (bits[20:10]) ----
    radix_select<8>(ghA, (uint32_t)TOPK, wtot, res, tid);
    const uint32_t prefix0 = res[0];
    const uint32_t needed0 = res[1];
    for (int i = tid; i < 2048; i += 256) sh[i] = 0;
    __syncthreads();
    for (int p = 0; p < q; ++p) {
        if (sL[p] != lq) continue;
        const float base = sD[p] + MARGIN;
        if (nvalid) {
            const uint32_t bits = __float_as_uint(fmaxf(base - dqn, 0.0f));
            if ((bits >> 21) == prefix0) atomicAdd(&sh[(bits >> 10) & 0x7FFu], 1u);
        }
    }
    __syncthreads();
    for (int i = tid; i < 2048; i += 256) { uint32_t c = sh[i]; if (c) atomicAdd(&ghB[i], c); }
    grid.sync();

    // ---- P3: select pass 1 + histogram pass 2 (bits[9:0]) ----
    radix_select<8>(ghB, needed0, wtot, res, tid);
    const uint32_t prefix1 = (prefix0 << 11) | res[0];
    const uint32_t needed1 = res[1];
    for (int i = tid; i < 2048; i += 256) sh[i] = 0;
    __syncthreads();
    for (int p = 0; p < q; ++p) {
        if (sL[p] != lq) continue;
        const float base = sD[p] + MARGIN;
        if (nvalid) {
            const uint32_t bits = __float_as_uint(fmaxf(base - dqn, 0.0f));
            if ((bits >> 10) == prefix1) atomicAdd(&sh[bits & 0x3FFu], 1u);
        }
    }
    __syncthreads();
    for (int i = tid; i < 1024; i += 256) { uint32_t c = sh[i]; if (c) atomicAdd(&ghC[i], c); }
    grid.sync();

    // ---- P4: select pass 2 -> exact threshold T; sum v > T ----
    radix_select<4>(ghC, needed1, wtot, res, tid);
    const uint32_t T       = (prefix1 << 10) | res[0];
    const uint32_t needed2 = res[1];
    double acc = 0.0;
    for (int p = 0; p < q; ++p) {
        if (sL[p] != lq) continue;
        const float base = sD[p] + MARGIN;
        if (nvalid) {
            const float v = fmaxf(base - dqn, 0.0f);
            if (__float_as_uint(v) > T) acc += (double)v;
        }
    }
#pragma unroll
    for (int off = 32; off > 0; off >>= 1) acc += __shfl_down(acc, off);
    if ((tid & 63) == 0) wsum[tid >> 6] = acc;
    __syncthreads();
    if (tid == 0) part[q] = wsum[0] + wsum[1] + wsum[2] + wsum[3];
    grid.sync();

    // ---- P5: final reduce (block 0 only) ----
    if (q == 0) {
        double a = part[tid];
#pragma unroll
        for (int off = 32; off > 0; off >>= 1) a += __shfl_down(a, off);
        if ((tid & 63) == 0) wsum[tid >> 6] = a;
        __syncthreads();
        if (tid == 0) {
            double s = wsum[0] + wsum[1] + wsum[2] + wsum[3];
            s += (double)needed2 * (double)__uint_as_float(T);
            out[0] = (float)(s / (double)TOPK);
        }
    }
}

extern "C" void kernel_launch(void* const* d_in, const int* in_sizes, int n_in,
                              void* d_out, int out_size, void* d_ws, size_t ws_size,
                              hipStream_t stream) {
    const float* x   = (const float*)d_in[0];
    const int*   lab = (const int*)d_in[1];
    float*       out = (float*)d_out;

    char* ws = (char*)d_ws;
    uint32_t* ghist = (uint32_t*)ws;
    double*   part  = (double*)(ws + 24576);

    void* args[] = {(void*)&x, (void*)&lab, (void*)&ghist, (void*)&part, (void*)&out};
    hipLaunchCooperativeKernel((const void*)fused_kernel, dim3(B), dim3(256),
                               args, 0, stream);
}

// Round 4
// 106.618 us; speedup vs baseline: 1.7817x; 1.7817x over previous
//
#include <hip/hip_runtime.h>
#include <stdint.h>

#define B 256
#define DIM 512
#define TOPK 4096
#define MARGIN 0.2f
#define SC_AGENT __HIP_MEMORY_SCOPE_AGENT

// ---------------- ws layout (all zeroed per call by hipMemsetAsync) --------
// ghA u32[2048] @ 0      ghB u32[2048] @ 8192    ghC u32[1024] @ 16384
// cnt u32[4]    @ 24576  pub u64[3]    @ 24592   part double[256] @ 24616 (not zeroed)
#define WS_ZERO_BYTES 24616

__device__ __forceinline__ uint32_t ld_rlx32(const uint32_t* p) {
    return __hip_atomic_load(p, __ATOMIC_RELAXED, SC_AGENT);
}
__device__ __forceinline__ uint64_t ld_rlx64(const uint64_t* p) {
    return __hip_atomic_load(p, __ATOMIC_RELAXED, SC_AGENT);
}

// Arrive at a phase boundary. The 256th arriver runs a parallel radix-select
// over the 256*PER-bucket global histogram (descending) and publishes
// (new_prefix << 13) | needed'  (always nonzero: needed' >= 1). Everyone else
// spins on the pre-zeroed slot with relaxed agent loads (value-carrying flag,
// no fences needed in the spin).
template <int PER>
__device__ uint64_t arrive_select(uint32_t* cnt, uint64_t* pub, const uint32_t* gh,
                                  uint32_t needed, uint32_t prefix, int shift,
                                  uint32_t* wtot, uint32_t* res, uint64_t* sPub,
                                  int* sLast, int tid) {
    if (tid == 0) {
        uint32_t old = __hip_atomic_fetch_add(cnt, 1u, __ATOMIC_ACQ_REL, SC_AGENT);
        *sLast = (old == B - 1) ? 1 : 0;
    }
    __syncthreads();
    if (*sLast) {
        // thread tid owns chunk (255-tid): inclusive scan over tid == suffix sums
        const int chunk = 255 - tid;
        uint32_t vals[PER];
        uint32_t v = 0;
#pragma unroll
        for (int k = 0; k < PER; ++k) { vals[k] = ld_rlx32(&gh[chunk * PER + k]); v += vals[k]; }
        uint32_t s = v;
        const int lane = tid & 63, wid = tid >> 6;
#pragma unroll
        for (int d = 1; d < 64; d <<= 1) {
            uint32_t t = __shfl_up(s, d, 64);
            if (lane >= d) s += t;
        }
        if (lane == 63) wtot[wid] = s;
        __syncthreads();
        uint32_t off = 0;
        for (int w = 0; w < wid; ++w) off += wtot[w];
        s += off;                       // count in buckets >= chunk*PER
        const uint32_t excl = s - v;    // count strictly above own chunk
        if (excl < needed && needed <= s) {
            uint32_t cum = excl;
#pragma unroll
            for (int k = PER - 1; k >= 0; --k) {
                const uint32_t h = vals[k];
                if (cum + h >= needed) {
                    res[0] = (uint32_t)(chunk * PER + k);
                    res[1] = needed - cum;
                    break;
                }
                cum += h;
            }
        }
        __syncthreads();
        if (tid == 0) {
            const uint32_t np = (prefix << shift) | res[0];
            const uint64_t packed = ((uint64_t)np << 13) | (uint64_t)res[1];
            __hip_atomic_store(pub, packed, __ATOMIC_RELEASE, SC_AGENT);
            *sPub = packed;
        }
    } else {
        if (tid == 0) {
            uint64_t v = ld_rlx64(pub);
            while (v == 0ull) { __builtin_amdgcn_s_sleep(1); v = ld_rlx64(pub); }
            *sPub = v;
        }
    }
    __syncthreads();
    return *sPub;
}

__global__ void __launch_bounds__(256, 1)
triplet_kernel(const float* __restrict__ x, const int* __restrict__ lab,
               uint32_t* __restrict__ gws, float* __restrict__ out) {
    uint32_t* ghA  = gws;
    uint32_t* ghB  = gws + 2048;
    uint32_t* ghC  = gws + 4096;
    uint32_t* cnt  = gws + 6144;
    uint64_t* pub  = (uint64_t*)(gws + 6148);   // byte 24592, 8-aligned
    double*   part = (double*)(gws + 6154);     // byte 24616, 8-aligned

    __shared__ float    sD[B];
    __shared__ int      sL[B];
    __shared__ uint32_t sh[2048];
    __shared__ float    pbase[B];
    __shared__ int      wcnt[4];
    __shared__ uint32_t wtot[4];
    __shared__ uint32_t res[2];
    __shared__ uint64_t sPub;
    __shared__ int      sLast;
    __shared__ int      pcnt_s;
    __shared__ double   wsum[4];

    const int q = blockIdx.x, tid = threadIdx.x;

    // ---- P0: D[q][tid] into LDS (row q only; fully block-local) ----
    {
        float* xi = (float*)sh;                 // alias sh as x_q staging
        for (int k = tid; k < DIM; k += 256) xi[k] = x[q * DIM + k];
        sL[tid] = lab[tid];
        __syncthreads();
        const float4* xj4 = (const float4*)(x + tid * DIM);
        float acc = 0.f;
#pragma unroll 4
        for (int k4 = 0; k4 < DIM / 4; ++k4) {
            float4 b = xj4[k4];
            float d0 = xi[k4 * 4 + 0] - b.x;
            float d1 = xi[k4 * 4 + 1] - b.y;
            float d2 = xi[k4 * 4 + 2] - b.z;
            float d3 = xi[k4 * 4 + 3] - b.w;
            acc += d0 * d0 + d1 * d1 + d2 * d2 + d3 * d3;
        }
        sD[tid] = acc;
    }
    __syncthreads();                            // xi reads done; sh reusable

    // ---- compact valid positives (p < q, same label) -> pbase, ascending p ----
    const int lq = sL[q];
    {
        const int lane = tid & 63, wv = tid >> 6;
        const bool pred = (tid < q) && (sL[tid] == lq);
        const uint64_t mask = __ballot(pred);
        if (lane == 0) wcnt[wv] = __popcll(mask);
        __syncthreads();
        int off = 0;
        for (int w = 0; w < wv; ++w) off += wcnt[w];
        if (pred) {
            const int pos = off + __popcll(mask & ((1ull << lane) - 1));
            pbase[pos] = sD[tid] + MARGIN;      // D[q][p] + margin, ascending p
        }
        if (tid == 0) pcnt_s = wcnt[0] + wcnt[1] + wcnt[2] + wcnt[3];
    }
    __syncthreads();
    const int   pcnt   = pcnt_s;
    const bool  nvalid = (sL[tid] != lq);
    const float dqn    = sD[tid];

    // ---- pass 0: bits[31:21] ----
    for (int i = tid; i < 2048; i += 256) sh[i] = 0;
    __syncthreads();
    if (nvalid) {
        for (int ip = 0; ip < pcnt; ++ip) {
            const uint32_t bits = __float_as_uint(fmaxf(pbase[ip] - dqn, 0.0f));
            atomicAdd(&sh[bits >> 21], 1u);
        }
    }
    __syncthreads();
    for (int i = tid; i < 2048; i += 256) { uint32_t c = sh[i]; if (c) atomicAdd(&ghA[i], c); }
    const uint64_t p0 = arrive_select<8>(cnt + 0, pub + 0, ghA, (uint32_t)TOPK, 0u, 11,
                                         wtot, res, &sPub, &sLast, tid);
    const uint32_t prefix0 = (uint32_t)(p0 >> 13);
    const uint32_t needed0 = (uint32_t)(p0 & 0x1FFFu);

    // ---- pass 1: bits[20:10] within prefix0 ----
    for (int i = tid; i < 2048; i += 256) sh[i] = 0;
    __syncthreads();
    if (nvalid) {
        for (int ip = 0; ip < pcnt; ++ip) {
            const uint32_t bits = __float_as_uint(fmaxf(pbase[ip] - dqn, 0.0f));
            if ((bits >> 21) == prefix0) atomicAdd(&sh[(bits >> 10) & 0x7FFu], 1u);
        }
    }
    __syncthreads();
    for (int i = tid; i < 2048; i += 256) { uint32_t c = sh[i]; if (c) atomicAdd(&ghB[i], c); }
    const uint64_t p1 = arrive_select<8>(cnt + 1, pub + 1, ghB, needed0, prefix0, 11,
                                         wtot, res, &sPub, &sLast, tid);
    const uint32_t prefix1 = (uint32_t)(p1 >> 13);
    const uint32_t needed1 = (uint32_t)(p1 & 0x1FFFu);

    // ---- pass 2: bits[9:0] within prefix1 ----
    for (int i = tid; i < 1024; i += 256) sh[i] = 0;
    __syncthreads();
    if (nvalid) {
        for (int ip = 0; ip < pcnt; ++ip) {
            const uint32_t bits = __float_as_uint(fmaxf(pbase[ip] - dqn, 0.0f));
            if ((bits >> 10) == prefix1) atomicAdd(&sh[bits & 0x3FFu], 1u);
        }
    }
    __syncthreads();
    for (int i = tid; i < 1024; i += 256) { uint32_t c = sh[i]; if (c) atomicAdd(&ghC[i], c); }
    const uint64_t p2 = arrive_select<4>(cnt + 2, pub + 2, ghC, needed1, prefix1, 10,
                                         wtot, res, &sPub, &sLast, tid);
    const uint32_t T       = (uint32_t)(p2 >> 13);   // exact threshold bits
    const uint32_t needed2 = (uint32_t)(p2 & 0x1FFFu);

    // ---- sum of v > T (fixed tree order -> deterministic) ----
    double acc = 0.0;
    if (nvalid) {
        for (int ip = 0; ip < pcnt; ++ip) {
            const float v = fmaxf(pbase[ip] - dqn, 0.0f);
            if (__float_as_uint(v) > T) acc += (double)v;
        }
    }
#pragma unroll
    for (int off = 32; off > 0; off >>= 1) acc += __shfl_down(acc, off);
    if ((tid & 63) == 0) wsum[tid >> 6] = acc;
    __syncthreads();
    if (tid == 0) {
        const double bs = wsum[0] + wsum[1] + wsum[2] + wsum[3];
        __hip_atomic_store(&part[q], bs, __ATOMIC_RELAXED, SC_AGENT);
        uint32_t old = __hip_atomic_fetch_add(cnt + 3, 1u, __ATOMIC_ACQ_REL, SC_AGENT);
        sLast = (old == B - 1) ? 1 : 0;
    }
    __syncthreads();
    if (sLast) {
        double a = __hip_atomic_load(&part[tid], __ATOMIC_RELAXED, SC_AGENT);
#pragma unroll
        for (int off = 32; off > 0; off >>= 1) a += __shfl_down(a, off);
        if ((tid & 63) == 0) wsum[tid >> 6] = a;
        __syncthreads();
        if (tid == 0) {
            double s = wsum[0] + wsum[1] + wsum[2] + wsum[3];
            s += (double)needed2 * (double)__uint_as_float(T);
            out[0] = (float)(s / (double)TOPK);
        }
    }
}

extern "C" void kernel_launch(void* const* d_in, const int* in_sizes, int n_in,
                              void* d_out, int out_size, void* d_ws, size_t ws_size,
                              hipStream_t stream) {
    const float* x   = (const float*)d_in[0];
    const int*   lab = (const int*)d_in[1];
    float*       out = (float*)d_out;
    uint32_t*    gws = (uint32_t*)d_ws;

    // zero hists + arrival counters + publish slots every call (graph memset node)
    hipMemsetAsync(gws, 0, WS_ZERO_BYTES, stream);

    void* args[] = {(void*)&x, (void*)&lab, (void*)&gws, (void*)&out};
    hipLaunchCooperativeKernel((const void*)triplet_kernel, dim3(B), dim3(256),
                               args, 0, stream);
}

// Round 5
// 88.533 us; speedup vs baseline: 2.1457x; 1.2043x over previous
//
#include <hip/hip_runtime.h>
#include <stdint.h>

#define B 256
#define DIM 512
#define TOPK 4096
#define MARGIN 0.2f
#define SC_AGENT __HIP_MEMORY_SCOPE_AGENT
#define BUFCAP 60000u
#define SBUF_CAP 12288
#define FIX_SCALE 68719476736.0   /* 2^36 */

// ---------------- ws layout ----------------
// ghA    u32[2048] @ 0      (zeroed)
// gFlags u32[256]  @ 8192   (zeroed)
// cnt1   u32       @ 9216   (zeroed)
// gCnt   u32       @ 9220   (zeroed)
// gSum   u64       @ 9224   (zeroed)
// buf    u32[BUFCAP] @ 9232 (not zeroed; first gCnt entries written each call)
#define WS_ZERO_BYTES 9232

__device__ __forceinline__ uint32_t ld_rlx32(const uint32_t* p) {
    return __hip_atomic_load(p, __ATOMIC_RELAXED, SC_AGENT);
}
__device__ __forceinline__ uint64_t ld_rlx64(const uint64_t* p) {
    return __hip_atomic_load(p, __ATOMIC_RELAXED, SC_AGENT);
}
__device__ __forceinline__ void st_rlx32(uint32_t* p, uint32_t v) {
    __hip_atomic_store(p, v, __ATOMIC_RELAXED, SC_AGENT);
}
__device__ __forceinline__ uint64_t fixv(float v) {
    return (uint64_t)((double)v * FIX_SCALE + 0.5);
}

// One radix-select step over a 256*PER-bucket histogram, descending order.
// Thread tid owns chunk (255-tid); inclusive shuffle-scan over tid == suffix
// sums over buckets. Exactly one thread writes res[0]=bucket, res[1]=needed'.
// GLOBAL: read histogram via relaxed agent atomic loads (coherence point).
template <int PER, bool GLOBAL>
__device__ void selstep(const uint32_t* h, uint32_t needed,
                        uint32_t* wtot, uint32_t* res, int tid) {
    const int chunk = 255 - tid;
    uint32_t vals[PER];
    uint32_t v = 0;
#pragma unroll
    for (int k = 0; k < PER; ++k) {
        vals[k] = GLOBAL ? ld_rlx32(&h[chunk * PER + k]) : h[chunk * PER + k];
        v += vals[k];
    }
    uint32_t s = v;
    const int lane = tid & 63, wid = tid >> 6;
#pragma unroll
    for (int d = 1; d < 64; d <<= 1) {
        uint32_t t = __shfl_up(s, d, 64);
        if (lane >= d) s += t;
    }
    if (lane == 63) wtot[wid] = s;
    __syncthreads();
    uint32_t off = 0;
    for (int w = 0; w < wid; ++w) off += wtot[w];
    s += off;                       // count in buckets >= chunk*PER
    const uint32_t excl = s - v;    // count strictly above own chunk
    if (excl < needed && needed <= s) {
        uint32_t cum = excl;
#pragma unroll
        for (int k = PER - 1; k >= 0; --k) {
            const uint32_t hv = vals[k];
            if (cum + hv >= needed) {
                res[0] = (uint32_t)(chunk * PER + k);
                res[1] = needed - cum;
                break;
            }
            cum += hv;
        }
    }
    __syncthreads();
}

__global__ void __launch_bounds__(256, 1)
triplet_kernel(const float* __restrict__ x, const int* __restrict__ lab,
               uint32_t* __restrict__ gws, float* __restrict__ out) {
    uint32_t* ghA    = gws;
    uint32_t* gFlags = gws + 2048;
    uint32_t* cnt1   = gws + 2304;
    uint32_t* gCnt   = gws + 2305;
    uint64_t* gSum   = (uint64_t*)(gws + 2306);   // byte 9224, 8-aligned
    uint32_t* buf    = gws + 2308;                // byte 9232

    __shared__ uint32_t sh[2048];
    __shared__ uint32_t sbuf[SBUF_CAP];           // 48 KiB; also x_q staging
    __shared__ float    sD[B];
    __shared__ int      sL[B];
    __shared__ float    pbase[B];
    __shared__ int      wcnt[4];
    __shared__ uint32_t wtot[4];
    __shared__ uint32_t res[2];
    __shared__ unsigned long long usum[4];
    __shared__ int      pcnt_s;
    __shared__ int      sFin;

    const int q = blockIdx.x, tid = threadIdx.x;
    const int lane = tid & 63, wv = tid >> 6;

    // ---- P0: D[q][tid] into LDS (block-local) ----
    {
        float* xi = (float*)sbuf;
        for (int k = tid; k < DIM; k += 256) xi[k] = x[q * DIM + k];
        sL[tid] = lab[tid];
        __syncthreads();
        const float4* xj4 = (const float4*)(x + tid * DIM);
        float acc = 0.f;
#pragma unroll 4
        for (int k4 = 0; k4 < DIM / 4; ++k4) {
            float4 b = xj4[k4];
            float d0 = xi[k4 * 4 + 0] - b.x;
            float d1 = xi[k4 * 4 + 1] - b.y;
            float d2 = xi[k4 * 4 + 2] - b.z;
            float d3 = xi[k4 * 4 + 3] - b.w;
            acc += d0 * d0 + d1 * d1 + d2 * d2 + d3 * d3;
        }
        sD[tid] = acc;
    }
    __syncthreads();

    // ---- compact valid positives (p < q, same label) -> pbase, ascending ----
    const int lq = sL[q];
    {
        const bool pred = (tid < q) && (sL[tid] == lq);
        const uint64_t mask = __ballot(pred);
        if (lane == 0) wcnt[wv] = __popcll(mask);
        __syncthreads();
        int off = 0;
        for (int w = 0; w < wv; ++w) off += wcnt[w];
        if (pred) {
            const int pos = off + __popcll(mask & ((1ull << lane) - 1));
            pbase[pos] = sD[tid] + MARGIN;
        }
        if (tid == 0) pcnt_s = wcnt[0] + wcnt[1] + wcnt[2] + wcnt[3];
    }
    __syncthreads();
    const int   pcnt   = pcnt_s;
    const bool  nvalid = (sL[tid] != lq);
    const float dqn    = sD[tid];

    // ---- P1: histogram of bits[31:21], merge to global ----
    for (int i = tid; i < 2048; i += 256) sh[i] = 0;
    __syncthreads();
    if (nvalid) {
        for (int ip = 0; ip < pcnt; ++ip) {
            const uint32_t bits = __float_as_uint(fmaxf(pbase[ip] - dqn, 0.0f));
            atomicAdd(&sh[bits >> 21], 1u);
        }
    }
    __syncthreads();
    for (int i = tid; i < 2048; i += 256) {
        uint32_t c = sh[i];
        if (c) atomicAdd(&ghA[i], c);
    }
    __syncthreads();   // all waves' atomics retired (vmcnt drained at barrier)
    if (tid == 0) __hip_atomic_store(&gFlags[q], 1u, __ATOMIC_RELEASE, SC_AGENT);

    // ---- single grid barrier: poll all 256 flags ----
    for (;;) {
        const uint32_t f = ld_rlx32(&gFlags[tid]);
        if (__syncthreads_count(f != 0) == B) break;
        __builtin_amdgcn_s_sleep(2);
    }
    asm volatile("" ::: "memory");

    // ---- redundant parallel select (every block; no publish round-trip) ----
    selstep<8, true>(ghA, (uint32_t)TOPK, wtot, res, tid);
    const uint32_t s0      = res[0];
    const uint32_t needed0 = res[1];

    // ---- P2: fixed-point sum above bucket + append in-bucket values ----
    {
        uint64_t sumA = 0;
        for (int ip = 0; ip < pcnt; ++ip) {
            bool inb = false;
            uint32_t bits = 0;
            if (nvalid) {
                const float v = fmaxf(pbase[ip] - dqn, 0.0f);
                bits = __float_as_uint(v);
                const uint32_t bk = bits >> 21;
                if (bk > s0) sumA += fixv(v);
                inb = (bk == s0);
            }
            const uint64_t m = __ballot(inb);
            if (m) {
                const int leader = __ffsll((unsigned long long)m) - 1;
                uint32_t base0;
                if (lane == leader) base0 = atomicAdd(gCnt, (uint32_t)__popcll(m));
                base0 = __shfl(base0, leader, 64);
                if (inb) {
                    const uint32_t pos = base0 + (uint32_t)__popcll(m & ((1ull << lane) - 1));
                    if (pos < BUFCAP) st_rlx32(&buf[pos], bits);
                }
            }
        }
#pragma unroll
        for (int off = 32; off > 0; off >>= 1)
            sumA += __shfl_down((unsigned long long)sumA, off, 64);
        if (lane == 0 && sumA)
            atomicAdd((unsigned long long*)gSum, (unsigned long long)sumA);
    }
    __syncthreads();   // drain appends/atomics of all waves
    if (tid == 0) {
        const uint32_t old = __hip_atomic_fetch_add(cnt1, 1u, __ATOMIC_ACQ_REL, SC_AGENT);
        sFin = (old == B - 1) ? 1 : 0;
    }
    __syncthreads();
    if (!sFin) return;   // 255 blocks exit; no spinning

    // ---- finalizer: exact select among in-bucket values (block-local) ----
    const int nbuf = (int)min(ld_rlx32(gCnt), BUFCAP);
    const int nst  = nbuf < SBUF_CAP ? nbuf : SBUF_CAP;
    for (int i = tid; i < nst; i += 256) sbuf[i] = ld_rlx32(&buf[i]);
    for (int i = tid; i < 2048; i += 256) sh[i] = 0;
    __syncthreads();
    auto getv = [&](int i) -> uint32_t {
        return (i < SBUF_CAP) ? sbuf[i] : ld_rlx32(&buf[i]);
    };

    // level 2: bits[20:10]
    for (int i = tid; i < nbuf; i += 256) atomicAdd(&sh[(getv(i) >> 10) & 0x7FFu], 1u);
    __syncthreads();
    selstep<8, false>(sh, needed0, wtot, res, tid);
    const uint32_t s1      = res[0];
    const uint32_t needed1 = res[1];

    // level 3: bits[9:0] within s1
    for (int i = tid; i < 1024; i += 256) sh[i] = 0;
    __syncthreads();
    for (int i = tid; i < nbuf; i += 256) {
        const uint32_t b = getv(i);
        if (((b >> 10) & 0x7FFu) == s1) atomicAdd(&sh[b & 0x3FFu], 1u);
    }
    __syncthreads();
    selstep<4, false>(sh, needed1, wtot, res, tid);
    const uint32_t s2      = res[0];
    const uint32_t needed2 = res[1];
    const uint32_t T = (s0 << 21) | (s1 << 10) | s2;

    // in-bucket fixed-point sum of values strictly above T
    uint64_t sb = 0;
    for (int i = tid; i < nbuf; i += 256) {
        const uint32_t b = getv(i);
        if (b > T) sb += fixv(__uint_as_float(b));
    }
#pragma unroll
    for (int off = 32; off > 0; off >>= 1)
        sb += __shfl_down((unsigned long long)sb, off, 64);
    if (lane == 0) usum[wv] = sb;
    __syncthreads();
    if (tid == 0) {
        const uint64_t total = usum[0] + usum[1] + usum[2] + usum[3] + ld_rlx64(gSum);
        const double tval = (double)__uint_as_float(T);
        const double loss = ((double)total * (1.0 / FIX_SCALE) +
                             (double)needed2 * tval) / (double)TOPK;
        out[0] = (float)loss;
    }
}

extern "C" void kernel_launch(void* const* d_in, const int* in_sizes, int n_in,
                              void* d_out, int out_size, void* d_ws, size_t ws_size,
                              hipStream_t stream) {
    const float* x   = (const float*)d_in[0];
    const int*   lab = (const int*)d_in[1];
    float*       out = (float*)d_out;
    uint32_t*    gws = (uint32_t*)d_ws;

    hipMemsetAsync(gws, 0, WS_ZERO_BYTES, stream);

    void* args[] = {(void*)&x, (void*)&lab, (void*)&gws, (void*)&out};
    hipLaunchCooperativeKernel((const void*)triplet_kernel, dim3(B), dim3(256),
                               args, 0, stream);
}

// Round 6
// 70.884 us; speedup vs baseline: 2.6800x; 1.2490x over previous
//
#include <hip/hip_runtime.h>
#include <stdint.h>

#define B 256
#define DIM 512
#define TOPK 4096
#define MARGIN 0.2f
#define SC_AGENT __HIP_MEMORY_SCOPE_AGENT
#define BUFCAP 60000u
#define FIX_SCALE 68719476736.0   /* 2^36 */

// ---------------- ws layout (zeroed region per call via hipMemsetAsync) ----
// ghA   u32[2048]  @ 0       ghB  u32[2048] @ 8192   gSumB u64[2048] @ 16384
// gFlags u32[256]  @ 32768   gSum u64 @ 33792   gCnt u32 @ 33800   cnt1 @ 33804
// buf   u32[BUFCAP] @ 33808  (not zeroed)
#define WS_ZERO_BYTES 33808

__device__ __forceinline__ uint32_t ld_rlx32(const uint32_t* p) {
    return __hip_atomic_load(p, __ATOMIC_RELAXED, SC_AGENT);
}
__device__ __forceinline__ uint64_t ld_rlx64(const uint64_t* p) {
    return __hip_atomic_load(p, __ATOMIC_RELAXED, SC_AGENT);
}
__device__ __forceinline__ void st_rlx32(uint32_t* p, uint32_t v) {
    __hip_atomic_store(p, v, __ATOMIC_RELAXED, SC_AGENT);
}
__device__ __forceinline__ uint64_t fixv(float v) {
    return (uint64_t)((double)v * FIX_SCALE + 0.5);
}

// One radix-select step over a 256*PER-bucket histogram, descending order.
// Thread tid owns chunk (255-tid); inclusive shuffle-scan over tid == suffix
// sums over buckets. Exactly one thread writes res[0]=bucket, res[1]=needed'.
template <int PER, bool GLOBAL>
__device__ void selstep(const uint32_t* h, uint32_t needed,
                        uint32_t* wtot, uint32_t* res, int tid) {
    const int chunk = 255 - tid;
    uint32_t vals[PER];
    uint32_t v = 0;
#pragma unroll
    for (int k = 0; k < PER; ++k) {
        vals[k] = GLOBAL ? ld_rlx32(&h[chunk * PER + k]) : h[chunk * PER + k];
        v += vals[k];
    }
    uint32_t s = v;
    const int lane = tid & 63, wid = tid >> 6;
#pragma unroll
    for (int d = 1; d < 64; d <<= 1) {
        uint32_t t = __shfl_up(s, d, 64);
        if (lane >= d) s += t;
    }
    if (lane == 63) wtot[wid] = s;
    __syncthreads();
    uint32_t off = 0;
    for (int w = 0; w < wid; ++w) off += wtot[w];
    s += off;                       // count in buckets >= chunk*PER
    const uint32_t excl = s - v;    // count strictly above own chunk
    if (excl < needed && needed <= s) {
        uint32_t cum = excl;
#pragma unroll
        for (int k = PER - 1; k >= 0; --k) {
            const uint32_t hv = vals[k];
            if (cum + hv >= needed) {
                res[0] = (uint32_t)(chunk * PER + k);
                res[1] = needed - cum;
                break;
            }
            cum += hv;
        }
    }
    __syncthreads();
}

__global__ void __launch_bounds__(256, 1)
triplet_kernel(const float* __restrict__ x, const int* __restrict__ lab,
               uint32_t* __restrict__ gws, float* __restrict__ out) {
    uint32_t* ghA    = gws;
    uint32_t* ghB    = gws + 2048;
    uint64_t* gSumB  = (uint64_t*)(gws + 4096);
    uint32_t* gFlags = gws + 8192;
    uint64_t* gSum   = (uint64_t*)(gws + 8448);
    uint32_t* gCnt   = gws + 8450;
    uint32_t* cnt1   = gws + 8451;
    uint32_t* buf    = gws + 8452;

    __shared__ uint32_t sh[2048];                 // hists (also x_q staging)
    __shared__ unsigned long long ssum[2048];     // fixed-point sum-hist
    __shared__ float    sD[B];
    __shared__ int      sL[B];
    __shared__ float    pbase[B];
    __shared__ int      wcnt[4];
    __shared__ uint32_t wtot[4];
    __shared__ uint32_t res[2];
    __shared__ unsigned long long usum[4];
    __shared__ uint32_t sBase;
    __shared__ int      pcnt_s;
    __shared__ int      sFin;

    const int q = blockIdx.x, tid = threadIdx.x;
    const int lane = tid & 63, wv = tid >> 6;

    // ---- P0: D[q][tid] into LDS (block-local) ----
    {
        float* xi = (float*)sh;
        for (int k = tid; k < DIM; k += 256) xi[k] = x[q * DIM + k];
        sL[tid] = lab[tid];
        __syncthreads();
        const float4* xj4 = (const float4*)(x + tid * DIM);
        float acc = 0.f;
#pragma unroll 4
        for (int k4 = 0; k4 < DIM / 4; ++k4) {
            float4 b = xj4[k4];
            float d0 = xi[k4 * 4 + 0] - b.x;
            float d1 = xi[k4 * 4 + 1] - b.y;
            float d2 = xi[k4 * 4 + 2] - b.z;
            float d3 = xi[k4 * 4 + 3] - b.w;
            acc += d0 * d0 + d1 * d1 + d2 * d2 + d3 * d3;
        }
        sD[tid] = acc;
    }
    __syncthreads();

    // ---- compact valid positives (p < q, same label) -> pbase ----
    const int lq = sL[q];
    {
        const bool pred = (tid < q) && (sL[tid] == lq);
        const uint64_t mask = __ballot(pred);
        if (lane == 0) wcnt[wv] = __popcll(mask);
        __syncthreads();
        int off = 0;
        for (int w = 0; w < wv; ++w) off += wcnt[w];
        if (pred) {
            const int pos = off + __popcll(mask & ((1ull << lane) - 1));
            pbase[pos] = sD[tid] + MARGIN;
        }
        if (tid == 0) pcnt_s = wcnt[0] + wcnt[1] + wcnt[2] + wcnt[3];
    }
    __syncthreads();
    const int   pcnt   = pcnt_s;
    const bool  nvalid = (sL[tid] != lq);
    const float dqn    = sD[tid];

    // ---- P1: histogram of bits[31:21], merge nonzero to ghA ----
    for (int i = tid; i < 2048; i += 256) sh[i] = 0;
    __syncthreads();
    if (nvalid) {
        for (int ip = 0; ip < pcnt; ++ip) {
            const uint32_t bits = __float_as_uint(fmaxf(pbase[ip] - dqn, 0.0f));
            atomicAdd(&sh[bits >> 21], 1u);
        }
    }
    __syncthreads();
    for (int i = tid; i < 2048; i += 256) {
        const uint32_t c = sh[i];
        if (c) atomicAdd(&ghA[i], c);
    }
    __syncthreads();   // all waves' global atomics retired before flag
    if (tid == 0) __hip_atomic_store(&gFlags[q], 1u, __ATOMIC_RELEASE, SC_AGENT);

    // ---- single grid barrier: poll all 256 flags ----
    for (;;) {
        const uint32_t f = ld_rlx32(&gFlags[tid]);
        if (__syncthreads_count(f != 0) == B) break;
        __builtin_amdgcn_s_sleep(2);
    }
    asm volatile("" ::: "memory");

    // ---- redundant parallel select of s0 (every block) ----
    selstep<8, true>(ghA, (uint32_t)TOPK, wtot, res, tid);
    const uint32_t s0      = res[0];
    const uint32_t needed0 = res[1];

    // ---- P2: level-2 count+sum hists (LDS) + above-bucket sum + count ----
    for (int i = tid; i < 2048; i += 256) { sh[i] = 0; ssum[i] = 0ull; }
    __syncthreads();
    uint64_t sumA = 0;
    uint32_t cin  = 0;
    if (nvalid) {
        for (int ip = 0; ip < pcnt; ++ip) {
            const float v = fmaxf(pbase[ip] - dqn, 0.0f);
            const uint32_t bits = __float_as_uint(v);
            const uint32_t bk = bits >> 21;
            if (bk > s0) {
                sumA += fixv(v);
            } else if (bk == s0) {
                const uint32_t b2 = (bits >> 10) & 0x7FFu;
                atomicAdd(&sh[b2], 1u);
                atomicAdd(&ssum[b2], (unsigned long long)fixv(v));
                ++cin;
            }
        }
    }
    // block exclusive scan of cin -> per-thread offset + one gCnt reservation
    {
        uint32_t inc = cin;
#pragma unroll
        for (int d = 1; d < 64; d <<= 1) {
            uint32_t t = __shfl_up(inc, d, 64);
            if (lane >= d) inc += t;
        }
        if (lane == 63) wcnt[wv] = (int)inc;
        __syncthreads();
        uint32_t woff = 0;
        for (int w = 0; w < wv; ++w) woff += (uint32_t)wcnt[w];
        const uint32_t myoff = woff + inc - cin;
        const uint32_t blockTot =
            (uint32_t)(wcnt[0] + wcnt[1] + wcnt[2] + wcnt[3]);
        if (tid == 0) sBase = blockTot ? atomicAdd(gCnt, blockTot) : 0u;
        __syncthreads();
        if (nvalid && cin) {
            uint32_t o = sBase + myoff;
            for (int ip = 0; ip < pcnt; ++ip) {
                const uint32_t bits =
                    __float_as_uint(fmaxf(pbase[ip] - dqn, 0.0f));
                if ((bits >> 21) == s0) {
                    if (o < BUFCAP) st_rlx32(&buf[o], bits);
                    ++o;
                }
            }
        }
    }
    // block-reduce sumA -> one gSum RMW per block
#pragma unroll
    for (int off = 32; off > 0; off >>= 1)
        sumA += __shfl_down((unsigned long long)sumA, off, 64);
    if (lane == 0) usum[wv] = sumA;
    __syncthreads();
    if (tid == 0) {
        const unsigned long long bt = usum[0] + usum[1] + usum[2] + usum[3];
        if (bt) atomicAdd((unsigned long long*)gSum, bt);
    }
    // merge nonzero level-2 hists to global
    for (int i = tid; i < 2048; i += 256) {
        const uint32_t c = sh[i];
        if (c) {
            atomicAdd(&ghB[i], c);
            atomicAdd((unsigned long long*)&gSumB[i], ssum[i]);
        }
    }
    __syncthreads();   // drain all waves' global ops before arrival
    if (tid == 0) {
        const uint32_t old =
            __hip_atomic_fetch_add(cnt1, 1u, __ATOMIC_RELEASE, SC_AGENT);
        sFin = (old == B - 1) ? 1 : 0;
    }
    __syncthreads();
    if (!sFin) return;   // 255 blocks exit; no spinning

    // ================= finalizer (one block) =================
    // level-2 select
    selstep<8, true>(ghB, needed0, wtot, res, tid);
    const uint32_t s1      = res[0];
    const uint32_t needed1 = res[1];

    // sum of level-2 buckets strictly above s1
    uint64_t sb2 = 0;
    for (int k = 0; k < 8; ++k) {
        const uint32_t b = (uint32_t)tid * 8u + (uint32_t)k;
        if (b > s1) sb2 += ld_rlx64(&gSumB[b]);
    }
#pragma unroll
    for (int off = 32; off > 0; off >>= 1)
        sb2 += __shfl_down((unsigned long long)sb2, off, 64);
    if (lane == 0) usum[wv] = sb2;
    __syncthreads();
    const uint64_t sumB2 = usum[0] + usum[1] + usum[2] + usum[3];
    __syncthreads();

    // single stream over buf: level-3 count+sum hists for values in (s0,s1)
    const uint32_t nbuf = min(ld_rlx32(gCnt), BUFCAP);
    for (int i = tid; i < 1024; i += 256) { sh[i] = 0; ssum[i] = 0ull; }
    __syncthreads();
    for (uint32_t i = (uint32_t)tid; i < nbuf; i += 256) {
        const uint32_t b = ld_rlx32(&buf[i]);
        if (((b >> 10) & 0x7FFu) == s1) {
            const uint32_t b3 = b & 0x3FFu;
            atomicAdd(&sh[b3], 1u);
            atomicAdd(&ssum[b3], (unsigned long long)fixv(__uint_as_float(b)));
        }
    }
    __syncthreads();
    selstep<4, false>(sh, needed1, wtot, res, tid);
    const uint32_t s2      = res[0];
    const uint32_t needed2 = res[1];
    const uint32_t T = (s0 << 21) | (s1 << 10) | s2;

    // sum of level-3 buckets strictly above s2 (values in bucket s2 == T)
    uint64_t sb3 = 0;
    for (int k = 0; k < 4; ++k) {
        const uint32_t b = (uint32_t)tid * 4u + (uint32_t)k;
        if (b > s2) sb3 += ssum[b];
    }
#pragma unroll
    for (int off = 32; off > 0; off >>= 1)
        sb3 += __shfl_down((unsigned long long)sb3, off, 64);
    if (lane == 0) usum[wv] = sb3;
    __syncthreads();
    if (tid == 0) {
        const uint64_t total =
            usum[0] + usum[1] + usum[2] + usum[3] + sumB2 + ld_rlx64(gSum);
        const double tval = (double)__uint_as_float(T);
        const double loss = ((double)total * (1.0 / FIX_SCALE) +
                             (double)needed2 * tval) / (double)TOPK;
        out[0] = (float)loss;
    }
}

extern "C" void kernel_launch(void* const* d_in, const int* in_sizes, int n_in,
                              void* d_out, int out_size, void* d_ws, size_t ws_size,
                              hipStream_t stream) {
    const float* x   = (const float*)d_in[0];
    const int*   lab = (const int*)d_in[1];
    float*       out = (float*)d_out;
    uint32_t*    gws = (uint32_t*)d_ws;

    hipMemsetAsync(gws, 0, WS_ZERO_BYTES, stream);

    void* args[] = {(void*)&x, (void*)&lab, (void*)&gws, (void*)&out};
    hipLaunchCooperativeKernel((const void*)triplet_kernel, dim3(B), dim3(256),
                               args, 0, stream);
}